// Round 20
// baseline (63.684 us; speedup 1.0000x reference)
//
#include <hip/hip_runtime.h>
#include <stdint.h>

// Causal self-attention: x[8,2048,256] fp32, W_attn[768,256], W_proj[256,256]
// cvt->bf16 fragment tiles, QKV GEMM (dense loads/stores, K pre-scaled),
// flash attn: 1024 blocks x 4 waves on paired chunks {2m,2m+1} x key-halves;
// per-tile K/V staged ONCE into LDS via async global_load_lds (double-buffer,
// zero-VGPR prefetch); 32x32x16 swapped-QK, fixed-max softmax, additive LDS
// combine (arrays aliased into staging LDS). proj GEMM.
//
// Fragment tile layout (A/B operands): 1KB tiles, lane-linear 16B/lane.
// Attn fragment layouts (per bh, 131072 elems):
//  Qf: [chunk32][sblk=d>>4][q&31][d&15]
//  Kf: [tile64][sblk=d>>4][key&63][d&15]
//  Vf: [tile64][kblk=(s>>4)&3][d][s&15]

#define BB 8
#define SS 2048
#define CC 256
#define HH 4
#define DD 64

typedef __attribute__((ext_vector_type(8))) __bf16 bf16x8;
typedef __attribute__((ext_vector_type(4))) __bf16 bf16x4;
typedef __attribute__((ext_vector_type(4))) float f32x4;
typedef __attribute__((ext_vector_type(16))) float f32x16;

#define CM 0.18033688011112042f   // (1/sqrt(64)) * log2(e), folded into K

static __device__ __forceinline__ uint32_t cvtpk(float lo, float hi) {
  uint32_t r;
  asm("v_cvt_pk_bf16_f32 %0, %1, %2" : "=v"(r) : "v"(lo), "v"(hi));
  return r;
}
static __device__ __forceinline__ void pl32swap(uint32_t& a, uint32_t& b) {
  asm("v_permlane32_swap_b32 %0, %1" : "+v"(a), "+v"(b));
}
union PU { uint32_t u[4]; bf16x8 v; };

static __device__ __forceinline__ int frag_off(int row, int c8) {
  return ((row >> 4) * 8 + (c8 >> 2)) * 512 + (row & 15) * 32 + (c8 & 3) * 8;
}

// ---------------- fused fp32 -> bf16 convert into fragment tiles ------------
__global__ __launch_bounds__(256) void cvt3_kernel(const float* __restrict__ x,
                                                   const float* __restrict__ wa,
                                                   const float* __restrict__ wp,
                                                   __bf16* __restrict__ xf,
                                                   __bf16* __restrict__ waf,
                                                   __bf16* __restrict__ wpf) {
  int i = blockIdx.x * blockDim.x + threadIdx.x;
  const float* in; __bf16* out;
  if (i < 524288) {
    in = x + i * 8;
    out = xf + frag_off(i >> 5, i & 31);
  } else if (i < 548864) {
    int j = i - 524288;
    in = wa + j * 8;
    out = waf + frag_off(j >> 5, j & 31);
  } else {
    int k = i - 548864;
    in = wp + k * 8;
    out = wpf + frag_off(k >> 5, k & 31);
  }
  float4 v0 = ((const float4*)in)[0];
  float4 v1 = ((const float4*)in)[1];
  bf16x8 o = { (__bf16)v0.x, (__bf16)v0.y, (__bf16)v0.z, (__bf16)v0.w,
               (__bf16)v1.x, (__bf16)v1.y, (__bf16)v1.z, (__bf16)v1.w };
  *(bf16x8*)out = o;
}

// ---------------- QKV GEMM: qkv = x @ W_attn^T -> Qf/Kf/Vf ----------------
__global__ __launch_bounds__(256) void qkv_gemm(const __bf16* __restrict__ xf,
                                                const __bf16* __restrict__ waf,
                                                __bf16* __restrict__ qf_,
                                                __bf16* __restrict__ kf_,
                                                __bf16* __restrict__ vf_) {
  const int lane = threadIdx.x & 63;
  const int ln = lane & 15, kg = lane >> 4;
  const int w = threadIdx.x >> 6;
  const int xs = blockIdx.x & 7;
  const int j = blockIdx.x >> 3;           // 0..95
  const int otile = j % 12;
  const int rt0 = (xs * 8 + j / 12) * 16 + w * 4;   // x row-tile (16 rows each)
  const int ot0 = otile * 4;               // W row-tile
  const int loff = ln * 32 + kg * 8;
  const bool vmode = (otile >= 8);

  f32x4 acc[4][4] = {};
  for (int cb = 0; cb < 8; ++cb) {
    bf16x8 a[4], wv[4];
#pragma unroll
    for (int i = 0; i < 4; ++i)
      a[i] = *(const bf16x8*)(xf + ((rt0 + i) * 8 + cb) * 512 + loff);
#pragma unroll
    for (int t = 0; t < 4; ++t)
      wv[t] = *(const bf16x8*)(waf + ((ot0 + t) * 8 + cb) * 512 + loff);
    if (vmode) {
#pragma unroll
      for (int i = 0; i < 4; ++i)
#pragma unroll
        for (int t = 0; t < 4; ++t)
          acc[i][t] = __builtin_amdgcn_mfma_f32_16x16x32_bf16(a[i], wv[t], acc[i][t], 0, 0, 0);
    } else {
#pragma unroll
      for (int i = 0; i < 4; ++i)
#pragma unroll
        for (int t = 0; t < 4; ++t)
          acc[i][t] = __builtin_amdgcn_mfma_f32_16x16x32_bf16(wv[t], a[i], acc[i][t], 0, 0, 0);
    }
  }
  const int r0 = rt0 * 16;
  const int o0 = ot0 * 16;
  if (!vmode) {
    const bool isK = (otile >= 4);
    const float sc = isK ? CM : 1.0f;
#pragma unroll
    for (int i = 0; i < 4; ++i) {
      int s = r0 + i * 16 + ln;
      int b = s >> 11, srow = s & 2047;
#pragma unroll
      for (int t = 0; t < 4; ++t) {
        int obase = o0 + t * 16 + kg * 4;     // +r consecutive
        int oo = obase & 255;
        int h = oo >> 6;
        int bh_off = (b * HH + h) * 131072;
        uint32_t lo = cvtpk(acc[i][t][0] * sc, acc[i][t][1] * sc);
        uint32_t hi2 = cvtpk(acc[i][t][2] * sc, acc[i][t][3] * sc);
        uint2 st = { lo, hi2 };
        if (!isK) {
          int off = bh_off + (srow >> 5) * 2048 + t * 512 + (srow & 31) * 16 + kg * 4;
          *(uint2*)(qf_ + off) = st;
        } else {
          int off = bh_off + (srow >> 6) * 4096 + t * 1024 + (srow & 63) * 16 + kg * 4;
          *(uint2*)(kf_ + off) = st;
        }
      }
    }
  } else {
    const int h = otile - 8;
#pragma unroll
    for (int i = 0; i < 4; ++i) {
      int sg = r0 + i * 16;                   // + kg*4 + r (low bits)
      int b = sg >> 11;
      int bh_off = (b * HH + h) * 131072;
      int sbase = (sg & 2047) + kg * 4;
      int off0 = bh_off + (sbase >> 6) * 4096 + ((sbase >> 4) & 3) * 1024 + (sbase & 15);
#pragma unroll
      for (int t = 0; t < 4; ++t) {
        int d = t * 16 + ln;
        uint32_t lo = cvtpk(acc[i][t][0], acc[i][t][1]);
        uint32_t hi2 = cvtpk(acc[i][t][2], acc[i][t][3]);
        uint2 st = { lo, hi2 };
        *(uint2*)(vf_ + off0 + d * 16) = st;
      }
    }
  }
}

// ---------------- Flash attention (async LDS staging, paired chunks) --------
// 1024 blocks x 4 waves. Waves {0,1}/{2,3} -> chunks 2m/2m+1 (key-halves 0/1).
// Per tile: 16KB K+V staged once into LDS dbuf via global_load_lds (zero-VGPR
// prefetch); compute of tile kt overlaps staging of kt+1; 1 barrier/tile.
__global__ __launch_bounds__(256, 4) void attn_kernel(const __bf16* __restrict__ qf_,
                                                      const __bf16* __restrict__ kf_,
                                                      const __bf16* __restrict__ vf_,
                                                      __bf16* __restrict__ yf) {
  __shared__ char smem[32768];         // 2 x (K 8KB + V 8KB); aliased for combine
  const int lane = threadIdx.x & 63;
  const int l31 = lane & 31;
  const int hi = lane >> 5;
  const int w = threadIdx.x >> 6;      // 0..3
  const int kh = w & 1;                // key-half within each 64-key tile
  const int cp = w >> 1;               // chunk-within-pair

  const int bid = blockIdx.x;
  const int xs = bid & 7;              // XCD slot
  const int j = bid >> 3;              // 0..127
  const int bh = xs + 8 * (j & 3);     // 4 bh per XCD
  const int p = j >> 2;                // 0..31 (pair id)
  const int c = (31 - p) * 2 + cp;     // longest pairs first
  const int q0w = c * 32;

  const int loff = l31 * 16 + hi * 8;  // lane offset within any 1KB fragment
  const int koff = kh * 32;            // this wave's key offset within a tile

  const __bf16* Qfb = qf_ + bh * 131072 + c * 2048 + loff;
  const __bf16* Kt = kf_ + bh * 131072;   // tile bases (no lane offset)
  const __bf16* Vt = vf_ + bh * 131072;

  bf16x8 qf[4];
#pragma unroll
  for (int s = 0; s < 4; ++s) qf[s] = *(const bf16x8*)(Qfb + s * 512);

  const int ntot = (q0w + 95) >> 6;    // 64-key tiles; equal across all 4 waves
  const int qrel = l31 + 32 * (c & 1);

  f32x16 acc0 = {}, acc1 = {};
  float lrun = 0.0f;

  // stage tile kt into LDS buffer `buf`: 16 chunks of 1KB, wave w owns 4.
  auto STAGE = [&](int buf, int kt) {
#pragma unroll
    for (int ci = 0; ci < 4; ++ci) {
      int ch = w * 4 + ci;
      const __bf16* g = (ch < 8 ? Kt + kt * 4096 + ch * 512
                                : Vt + kt * 4096 + (ch - 8) * 512) + lane * 8;
      char* l = smem + buf * 16384 + ch * 1024;
      __builtin_amdgcn_global_load_lds(
          (const __attribute__((address_space(1))) void*)g,
          (__attribute__((address_space(3))) void*)l, 16, 0, 0);
    }
  };

  STAGE(0, 0);
  __syncthreads();

  int cur = 0;
  for (int kt = 0; kt < ntot; ++kt) {
    if (kt + 1 < ntot) STAGE(cur ^ 1, kt + 1);   // async prefetch (no VGPRs)

    const __bf16* kl = (const __bf16*)(smem + cur * 16384);
    const __bf16* vl = (const __bf16*)(smem + cur * 16384 + 8192);

    // K half-fragments and V fragments from LDS
    bf16x8 ka[4], vfr[2][2];
#pragma unroll
    for (int s = 0; s < 4; ++s) ka[s] = *(const bf16x8*)(kl + kh * 512 + s * 1024 + loff);
    {
      const __bf16* vp = vl + kh * 2048 + loff;
      vfr[0][0] = *(const bf16x8*)(vp);
      vfr[0][1] = *(const bf16x8*)(vp + 512);
      vfr[1][0] = *(const bf16x8*)(vp + 1024);
      vfr[1][1] = *(const bf16x8*)(vp + 1536);
    }

    // QK^T (swapped): s0[r] = S[key = koff + crow(r,hi)][q = l31]
    f32x16 s0 = {};
    __builtin_amdgcn_s_setprio(1);
#pragma unroll
    for (int s = 0; s < 4; ++s) s0 = __builtin_amdgcn_mfma_f32_32x32x16_bf16(ka[s], qf[s], s0, 0, 0, 0);
    __builtin_amdgcn_s_setprio(0);

    if (kt == ntot - 1) {               // diagonal tile: per-lane causal mask
#pragma unroll
      for (int r = 0; r < 16; ++r) {
        int crow = (r & 3) + 8 * (r >> 2) + 4 * hi;
        s0[r] = (crow + koff <= qrel) ? s0[r] : -1e30f;
      }
    }

    // fixed-max softmax: P = exp2(s') (max cancels in the final divide)
#pragma unroll
    for (int r = 0; r < 16; ++r) s0[r] = __builtin_amdgcn_exp2f(s0[r]);

    // per-tile partial sum (transient tree; cross-half shfl deferred)
    {
      float sm[8];
#pragma unroll
      for (int r = 0; r < 8; ++r) sm[r] = s0[r] + s0[r + 8];
#pragma unroll
      for (int st = 4; st > 0; st >>= 1)
#pragma unroll
        for (int r = 0; r < 4; ++r) if (r < st) sm[r] += sm[r + st];
      lrun += sm[0];
    }

    // repack P -> B-fragments
    bf16x8 pf[2];
#pragma unroll
    for (int g = 0; g < 2; ++g) {
      const int o = g * 8;
      uint32_t a = cvtpk(s0[o + 0], s0[o + 1]);
      uint32_t b = cvtpk(s0[o + 4], s0[o + 5]);
      uint32_t c2 = cvtpk(s0[o + 2], s0[o + 3]);
      uint32_t d2 = cvtpk(s0[o + 6], s0[o + 7]);
      pl32swap(a, b);
      pl32swap(c2, d2);
      PU u; u.u[0] = a; u.u[1] = c2; u.u[2] = b; u.u[3] = d2;
      pf[g] = u.v;
    }

    // PV: acc[dh] += V^T[kblk][dh] . P[kblk]
    __builtin_amdgcn_s_setprio(1);
    acc0 = __builtin_amdgcn_mfma_f32_32x32x16_bf16(vfr[0][0], pf[0], acc0, 0, 0, 0);
    acc0 = __builtin_amdgcn_mfma_f32_32x32x16_bf16(vfr[1][0], pf[1], acc0, 0, 0, 0);
    acc1 = __builtin_amdgcn_mfma_f32_32x32x16_bf16(vfr[0][1], pf[0], acc1, 0, 0, 0);
    acc1 = __builtin_amdgcn_mfma_f32_32x32x16_bf16(vfr[1][1], pf[1], acc1, 0, 0, 0);
    __builtin_amdgcn_s_setprio(0);

    __syncthreads();                    // staging of kt+1 done; buf[cur] free
    cur ^= 1;
  }

  // deferred cross-half (hi) combine of the l partial sum
  lrun += __shfl_xor(lrun, 32);

  // ---- combine across key-halves (additive); LDS aliased over staging ----
  float* lsum = (float*)smem;                    // [2][32]
  float* lacc = (float*)(smem + 256);            // [2][64][33]
  if (kh == 1) {
    if (hi == 0) lsum[cp * 32 + l31] = lrun;
#pragma unroll
    for (int r = 0; r < 16; ++r) {
      int d0 = (r & 3) + 8 * (r >> 2) + 4 * hi;
      lacc[(cp * 64 + d0) * 33 + l31] = acc0[r];
      lacc[(cp * 64 + 32 + d0) * 33 + l31] = acc1[r];
    }
  }
  __syncthreads();
  if (kh == 0) {
    float L = lrun + lsum[cp * 32 + l31];
    float inv = __builtin_amdgcn_rcpf(L);
    const int b = bh >> 2, h = bh & 3;
    __bf16* ytile = yf + (((b * 128 + c * 2 + (l31 >> 4)) * 8 + h * 2) * 512)
                       + (l31 & 15) * 32 + hi * 4;
#pragma unroll
    for (int g = 0; g < 4; ++g) {
      float a0[4], a1[4];
#pragma unroll
      for (int i2 = 0; i2 < 4; ++i2) {
        int d0 = i2 + 8 * g + 4 * hi;
        a0[i2] = (acc0[g * 4 + i2] + lacc[(cp * 64 + d0) * 33 + l31]) * inv;
        a1[i2] = (acc1[g * 4 + i2] + lacc[(cp * 64 + 32 + d0) * 33 + l31]) * inv;
      }
      uint32_t w0 = cvtpk(a0[0], a0[1]);
      uint32_t w1 = cvtpk(a0[2], a0[3]);
      uint2 st0 = { w0, w1 };
      *(uint2*)(ytile + g * 8) = st0;
      w0 = cvtpk(a1[0], a1[1]);
      w1 = cvtpk(a1[2], a1[3]);
      uint2 st1 = { w0, w1 };
      *(uint2*)(ytile + 512 + g * 8) = st1;   // d+32 -> next col-block tile
    }
  }
}

// ---------------- Proj GEMM: out = y @ W_proj^T (fp32 out) ------------------
__global__ __launch_bounds__(256) void proj_gemm(const __bf16* __restrict__ yf,
                                                 const __bf16* __restrict__ wpf,
                                                 float* __restrict__ out) {
  const int lane = threadIdx.x & 63;
  const int ln = lane & 15, kg = lane >> 4;
  const int w = threadIdx.x >> 6;
  const int xs = blockIdx.x & 7;
  const int j = blockIdx.x >> 3;       // 0..31
  const int otile = j & 3;
  const int rt0 = (xs * 8 + (j >> 2)) * 16 + w * 4;
  const int ot0 = otile * 4;
  const int loff = ln * 32 + kg * 8;

  f32x4 acc[4][4] = {};
  for (int cb = 0; cb < 8; ++cb) {
    bf16x8 a[4], wv[4];
#pragma unroll
    for (int i = 0; i < 4; ++i)
      a[i] = *(const bf16x8*)(yf + ((rt0 + i) * 8 + cb) * 512 + loff);
#pragma unroll
    for (int t = 0; t < 4; ++t)
      wv[t] = *(const bf16x8*)(wpf + ((ot0 + t) * 8 + cb) * 512 + loff);
#pragma unroll
    for (int i = 0; i < 4; ++i)
#pragma unroll
      for (int t = 0; t < 4; ++t)
        acc[i][t] = __builtin_amdgcn_mfma_f32_16x16x32_bf16(a[i], wv[t], acc[i][t], 0, 0, 0);
  }
  const int r0 = rt0 * 16;
  const int o0 = ot0 * 16;
#pragma unroll
  for (int i = 0; i < 4; ++i)
#pragma unroll
    for (int t = 0; t < 4; ++t) {
      int o = o0 + t * 16 + ln;
#pragma unroll
      for (int r = 0; r < 4; ++r) {
        int rout = r0 + i * 16 + kg * 4 + r;
        out[rout * 256 + o] = acc[i][t][r];
      }
    }
}

extern "C" void kernel_launch(void* const* d_in, const int* in_sizes, int n_in,
                              void* d_out, int out_size, void* d_ws, size_t ws_size,
                              hipStream_t stream) {
  const float* x = (const float*)d_in[0];
  const float* Wa = (const float*)d_in[1];
  const float* Wp = (const float*)d_in[2];

  char* ws = (char*)d_ws;
  __bf16* xf  = (__bf16*)(ws);                    // 8 MiB  x fragment tiles
  __bf16* qfb = (__bf16*)(ws + 8388608);          // 8 MiB  Qf
  __bf16* kfb = (__bf16*)(ws + 16777216);         // 8 MiB  Kf (pre-scaled)
  __bf16* vfb = (__bf16*)(ws + 25165824);         // 8 MiB  Vf
  __bf16* yf  = (__bf16*)(ws + 33554432);         // 8 MiB  y fragment tiles
  __bf16* waf = (__bf16*)(ws + 41943040);         // 384 KiB W_attn fragment tiles
  __bf16* wpf = (__bf16*)(ws + 42336256);         // 128 KiB W_proj fragment tiles

  cvt3_kernel<<<2176, 256, 0, stream>>>(x, Wa, Wp, xf, waf, wpf);
  qkv_gemm<<<768, 256, 0, stream>>>(xf, waf, qfb, kfb, vfb);
  attn_kernel<<<1024, 256, 0, stream>>>(qfb, kfb, vfb, yf);
  proj_gemm<<<256, 256, 0, stream>>>(yf, wpf, (float*)d_out);
}